// Round 2
// baseline (322.631 us; speedup 1.0000x reference)
//
#include <hip/hip_runtime.h>

// NeRF raw2outputs, fp32 in/out, fp32 math.
// One wave (64 lanes) per ray; lane l owns samples {l, l+64, l+128}.
// Cross-lane ops on the VALU pipe via DPP (row_shr/row_bcast) + v_readlane.
// Memory: PLAIN cached loads (nt hints removed — no reuse to protect, and the
// 6.3-6.7 TB/s ceilings are measured with plain accesses); nt kept on the
// weights stream stores only.

#define NS 192
#define INF_DIST 1e10f

typedef float floatx4 __attribute__((ext_vector_type(4)));

// update_dpp: out-of-bounds / row_mask-disabled lanes receive `oldv` (identity).
#define DPPF(oldv, srcv, ctrl, rmask) \
    __int_as_float(__builtin_amdgcn_update_dpp( \
        __float_as_int(oldv), __float_as_int(srcv), (ctrl), (rmask), 0xf, false))

// DPP ctrl encodings (gfx9/CDNA): row_shl:N=0x100+N, row_shr:N=0x110+N,
// row_bcast15=0x142, row_bcast31=0x143.

__device__ __forceinline__ float readlane_f(float v, int l) {
    return __int_as_float(__builtin_amdgcn_readlane(__float_as_int(v), l));
}

// Inclusive 64-lane product scan, all on the VALU pipe (no DS ops).
__device__ __forceinline__ float mul_scan64(float v) {
    float p = v;
    p *= DPPF(1.0f, p, 0x111, 0xf);   // row_shr:1
    p *= DPPF(1.0f, p, 0x112, 0xf);   // row_shr:2
    p *= DPPF(1.0f, p, 0x114, 0xf);   // row_shr:4
    p *= DPPF(1.0f, p, 0x118, 0xf);   // row_shr:8  -> per-16-row inclusive scan
    p *= DPPF(1.0f, p, 0x142, 0xa);   // row_bcast15 -> rows 1,3
    p *= DPPF(1.0f, p, 0x143, 0xc);   // row_bcast31 -> rows 2,3
    return p;
}

// 64-lane sum reduction on the VALU pipe; total lands in lane 63.
__device__ __forceinline__ float sum_red64(float x) {
    x += DPPF(0.0f, x, 0x111, 0xf);
    x += DPPF(0.0f, x, 0x112, 0xf);
    x += DPPF(0.0f, x, 0x114, 0xf);
    x += DPPF(0.0f, x, 0x118, 0xf);
    x += DPPF(0.0f, x, 0x142, 0xa);
    x += DPPF(0.0f, x, 0x143, 0xc);
    return readlane_f(x, 63);
}

__global__ __launch_bounds__(256) void nerf_render(
    const floatx4* __restrict__ raw,   // [N, S] {r,g,b,sigma}
    const float*  __restrict__ z_vals, // [N, S]
    const float*  __restrict__ rays_d, // [N, 3]
    float* __restrict__ out,           // rgb(3N)|disp(N)|acc(N)|weights(192N)|depth(N)
    int N)
{
    const int lane = threadIdx.x & 63;
    const int ray  = (blockIdx.x << 2) + (threadIdx.x >> 6);  // 4 waves/block
    if (ray >= N) return;

    const float* zr = z_vals + (size_t)ray * NS;
    const floatx4* rr = raw + (size_t)ray * NS;

    // Interleave load issue so chunk-0 dependencies (z0, z1, r0) retire first.
    float zchunks[3];
    floatx4 rchunks[3];
    zchunks[0] = zr[lane];
    rchunks[0] = rr[lane];
    zchunks[1] = zr[lane + 64];
    rchunks[1] = rr[lane + 64];
    zchunks[2] = zr[lane + 128];
    rchunks[2] = rr[lane + 128];

    // ray-direction norm (uniform within wave; rays_d is tiny -> stays in L2)
    float dxv = rays_d[ray * 3 + 0];
    float dyv = rays_d[ray * 3 + 1];
    float dzv = rays_d[ray * 3 + 2];
    float norm = sqrtf(dxv * dxv + dyv * dyv + dzv * dzv);

    float* w_out = out + (size_t)N * 5 + (size_t)ray * NS;

    float chain = 1.0f;  // product of (1-alpha+eps) over previous chunks
    float racc = 0.f, gacc = 0.f, bacc = 0.f, dacc = 0.f, aacc = 0.f;

    #pragma unroll
    for (int k = 0; k < 3; ++k) {
        floatx4 rv = rchunks[k];
        float z = zchunks[k];

        // zn = z of next sample. row_shl:1 gives lane i <- lane i+1 within each
        // 16-row; seams (15,31,47) and the chunk boundary (63) via readlane.
        float zn = DPPF(z, z, 0x101, 0xf);                 // row_shl:1
        zn = (lane == 15) ? readlane_f(z, 16) : zn;
        zn = (lane == 31) ? readlane_f(z, 32) : zn;
        zn = (lane == 47) ? readlane_f(z, 48) : zn;
        if (k < 2) {
            float zf = readlane_f(zchunks[k + 1], 0);
            zn = (lane == 63) ? zf : zn;
        }
        float dist = (k == 2 && lane == 63) ? INF_DIST : (zn - z);
        dist *= norm;

        float sigma = fmaxf(rv.w, 0.0f);
        float e     = __expf(-sigma * dist);   // = 1 - alpha, exactly
        float alpha = 1.0f - e;
        float v     = e + 1e-10f;

        // inclusive product scan across 64 lanes (VALU/DPP, no DS pipe)
        float p = mul_scan64(v);

        // exclusive value: row_shr:1 handles within-row; fix seams 16/32/48.
        float ex = DPPF(1.0f, p, 0x111, 0xf);              // lane 0 -> 1.0
        ex = (lane == 16) ? readlane_f(p, 15) : ex;
        ex = (lane == 32) ? readlane_f(p, 31) : ex;
        ex = (lane == 48) ? readlane_f(p, 47) : ex;

        float T = chain * ex;
        float w = alpha * T;
        chain *= readlane_f(p, 63);                        // chunk total product

        // sigmoid via v_rcp_f32 (1 ulp; error << tolerance)
        racc += w * __builtin_amdgcn_rcpf(1.0f + __expf(-rv.x));
        gacc += w * __builtin_amdgcn_rcpf(1.0f + __expf(-rv.y));
        bacc += w * __builtin_amdgcn_rcpf(1.0f + __expf(-rv.z));
        dacc += w * z;
        aacc += w;

        __builtin_nontemporal_store(w, w_out + (k << 6) + lane);  // streaming store
    }

    // wave-wide sums on the VALU pipe (no DS ops)
    racc = sum_red64(racc);
    gacc = sum_red64(gacc);
    bacc = sum_red64(bacc);
    dacc = sum_red64(dacc);
    aacc = sum_red64(aacc);

    if (lane == 0) {
        float acc   = aacc;
        float depth = dacc;
        if (acc <= 1e-10f) depth = INF_DIST;
        float disp = 1.0f / fmaxf(1e-10f, depth / acc);  // acc==0 -> inf -> 0, matches np
        out[(size_t)ray * 3 + 0] = racc;
        out[(size_t)ray * 3 + 1] = gacc;
        out[(size_t)ray * 3 + 2] = bacc;
        out[(size_t)N * 3 + ray]   = disp;
        out[(size_t)N * 4 + ray]   = acc;
        out[(size_t)N * 197 + ray] = depth;
    }
}

extern "C" void kernel_launch(void* const* d_in, const int* in_sizes, int n_in,
                              void* d_out, int out_size, void* d_ws, size_t ws_size,
                              hipStream_t stream) {
    const floatx4* raw   = (const floatx4*)d_in[0];
    const float*  z_vals = (const float*)d_in[1];
    const float*  rays_d = (const float*)d_in[2];
    float* out = (float*)d_out;
    int N = in_sizes[2] / 3;                 // rays_d is [N,3]
    int blocks = (N + 3) / 4;                // 4 rays (waves) per 256-thread block
    hipLaunchKernelGGL(nerf_render, dim3(blocks), dim3(256), 0, stream,
                       raw, z_vals, rays_d, out, N);
}

// Round 3
// 301.183 us; speedup vs baseline: 1.0712x; 1.0712x over previous
//
#include <hip/hip_runtime.h>

// NeRF raw2outputs, fp32 in/out, fp32 math.
// One wave (64 lanes) per ray; lane l owns samples {l, l+64, l+128}.
// Cross-lane ops on the VALU pipe via DPP (row_shr/row_bcast) + v_readlane.
// Memory: NONTEMPORAL loads AND stores — measured A/B (R1 vs R2): plain cached
// loads cost +33% kernel time (L2/LLC allocation pressure on a 252MB read-once
// stream). nt keeps the caches out of the stream's way.

#define NS 192
#define INF_DIST 1e10f

typedef float floatx4 __attribute__((ext_vector_type(4)));

// update_dpp: out-of-bounds / row_mask-disabled lanes receive `oldv` (identity).
#define DPPF(oldv, srcv, ctrl, rmask) \
    __int_as_float(__builtin_amdgcn_update_dpp( \
        __float_as_int(oldv), __float_as_int(srcv), (ctrl), (rmask), 0xf, false))

// DPP ctrl encodings (gfx9/CDNA): row_shl:N=0x100+N, row_shr:N=0x110+N,
// row_bcast15=0x142, row_bcast31=0x143.

__device__ __forceinline__ float readlane_f(float v, int l) {
    return __int_as_float(__builtin_amdgcn_readlane(__float_as_int(v), l));
}

// Inclusive 64-lane product scan, all on the VALU pipe (no DS ops).
__device__ __forceinline__ float mul_scan64(float v) {
    float p = v;
    p *= DPPF(1.0f, p, 0x111, 0xf);   // row_shr:1
    p *= DPPF(1.0f, p, 0x112, 0xf);   // row_shr:2
    p *= DPPF(1.0f, p, 0x114, 0xf);   // row_shr:4
    p *= DPPF(1.0f, p, 0x118, 0xf);   // row_shr:8  -> per-16-row inclusive scan
    p *= DPPF(1.0f, p, 0x142, 0xa);   // row_bcast15 -> rows 1,3
    p *= DPPF(1.0f, p, 0x143, 0xc);   // row_bcast31 -> rows 2,3
    return p;
}

// 64-lane sum reduction on the VALU pipe; total lands in lane 63.
__device__ __forceinline__ float sum_red64(float x) {
    x += DPPF(0.0f, x, 0x111, 0xf);
    x += DPPF(0.0f, x, 0x112, 0xf);
    x += DPPF(0.0f, x, 0x114, 0xf);
    x += DPPF(0.0f, x, 0x118, 0xf);
    x += DPPF(0.0f, x, 0x142, 0xa);
    x += DPPF(0.0f, x, 0x143, 0xc);
    return readlane_f(x, 63);
}

__global__ __launch_bounds__(256) void nerf_render(
    const floatx4* __restrict__ raw,   // [N, S] {r,g,b,sigma}
    const float*  __restrict__ z_vals, // [N, S]
    const float*  __restrict__ rays_d, // [N, 3]
    float* __restrict__ out,           // rgb(3N)|disp(N)|acc(N)|weights(192N)|depth(N)
    int N)
{
    const int lane = threadIdx.x & 63;
    const int ray  = (blockIdx.x << 2) + (threadIdx.x >> 6);  // 4 waves/block
    if (ray >= N) return;

    // ray-direction norm (uniform within wave; rays_d is tiny -> keep cached)
    float dxv = rays_d[ray * 3 + 0];
    float dyv = rays_d[ray * 3 + 1];
    float dzv = rays_d[ray * 3 + 2];
    float norm = sqrtf(dxv * dxv + dyv * dyv + dzv * dzv);

    // z chunks: coalesced 4B/lane, streaming (nt = no cache allocation)
    const float* zr = z_vals + (size_t)ray * NS;
    float zchunks[3];
    zchunks[0] = __builtin_nontemporal_load(zr + lane);
    zchunks[1] = __builtin_nontemporal_load(zr + lane + 64);
    zchunks[2] = __builtin_nontemporal_load(zr + lane + 128);

    // raw chunks: 16B/lane, fully coalesced (1 KiB/wave/chunk), streaming
    const floatx4* rr = raw + (size_t)ray * NS;
    floatx4 rchunks[3];
    rchunks[0] = __builtin_nontemporal_load(rr + lane);
    rchunks[1] = __builtin_nontemporal_load(rr + lane + 64);
    rchunks[2] = __builtin_nontemporal_load(rr + lane + 128);

    float* w_out = out + (size_t)N * 5 + (size_t)ray * NS;

    float chain = 1.0f;  // product of (1-alpha+eps) over previous chunks
    float racc = 0.f, gacc = 0.f, bacc = 0.f, dacc = 0.f, aacc = 0.f;

    #pragma unroll
    for (int k = 0; k < 3; ++k) {
        floatx4 rv = rchunks[k];
        float z = zchunks[k];

        // zn = z of next sample. row_shl:1 gives lane i <- lane i+1 within each
        // 16-row; seams (15,31,47) and the chunk boundary (63) via readlane.
        float zn = DPPF(z, z, 0x101, 0xf);                 // row_shl:1
        zn = (lane == 15) ? readlane_f(z, 16) : zn;
        zn = (lane == 31) ? readlane_f(z, 32) : zn;
        zn = (lane == 47) ? readlane_f(z, 48) : zn;
        if (k < 2) {
            float zf = readlane_f(zchunks[k + 1], 0);
            zn = (lane == 63) ? zf : zn;
        }
        float dist = (k == 2 && lane == 63) ? INF_DIST : (zn - z);
        dist *= norm;

        float sigma = fmaxf(rv.w, 0.0f);
        float e     = __expf(-sigma * dist);   // = 1 - alpha, exactly
        float alpha = 1.0f - e;
        float v     = e + 1e-10f;

        // inclusive product scan across 64 lanes (VALU/DPP, no DS pipe)
        float p = mul_scan64(v);

        // exclusive value: row_shr:1 handles within-row; fix seams 16/32/48.
        float ex = DPPF(1.0f, p, 0x111, 0xf);              // lane 0 -> 1.0
        ex = (lane == 16) ? readlane_f(p, 15) : ex;
        ex = (lane == 32) ? readlane_f(p, 31) : ex;
        ex = (lane == 48) ? readlane_f(p, 47) : ex;

        float T = chain * ex;
        float w = alpha * T;
        chain *= readlane_f(p, 63);                        // chunk total product

        // sigmoid via v_rcp_f32 (1 ulp; error << tolerance)
        racc += w * __builtin_amdgcn_rcpf(1.0f + __expf(-rv.x));
        gacc += w * __builtin_amdgcn_rcpf(1.0f + __expf(-rv.y));
        bacc += w * __builtin_amdgcn_rcpf(1.0f + __expf(-rv.z));
        dacc += w * z;
        aacc += w;

        __builtin_nontemporal_store(w, w_out + (k << 6) + lane);  // streaming store
    }

    // wave-wide sums on the VALU pipe (no DS ops)
    racc = sum_red64(racc);
    gacc = sum_red64(gacc);
    bacc = sum_red64(bacc);
    dacc = sum_red64(dacc);
    aacc = sum_red64(aacc);

    if (lane == 0) {
        float acc   = aacc;
        float depth = dacc;
        if (acc <= 1e-10f) depth = INF_DIST;
        float disp = 1.0f / fmaxf(1e-10f, depth / acc);  // acc==0 -> inf -> 0, matches np
        out[(size_t)ray * 3 + 0] = racc;
        out[(size_t)ray * 3 + 1] = bacc == bacc ? gacc : gacc;  // keep simple, see below
        out[(size_t)ray * 3 + 1] = gacc;
        out[(size_t)ray * 3 + 2] = bacc;
        out[(size_t)N * 3 + ray]   = disp;
        out[(size_t)N * 4 + ray]   = acc;
        out[(size_t)N * 197 + ray] = depth;
    }
}

extern "C" void kernel_launch(void* const* d_in, const int* in_sizes, int n_in,
                              void* d_out, int out_size, void* d_ws, size_t ws_size,
                              hipStream_t stream) {
    const floatx4* raw   = (const floatx4*)d_in[0];
    const float*  z_vals = (const float*)d_in[1];
    const float*  rays_d = (const float*)d_in[2];
    float* out = (float*)d_out;
    int N = in_sizes[2] / 3;                 // rays_d is [N,3]
    int blocks = (N + 3) / 4;                // 4 rays (waves) per 256-thread block
    hipLaunchKernelGGL(nerf_render, dim3(blocks), dim3(256), 0, stream,
                       raw, z_vals, rays_d, out, N);
}